// Round 1
// 274.312 us; speedup vs baseline: 1.0894x; 1.0894x over previous
//
#include <hip/hip_runtime.h>

#define NUM_GRAPHS 512
#define NPG        1024
#define KSEL       512
#define NNODES     (NUM_GRAPHS * NPG)   // 524288
#define CFEAT      64
#define NEDGE      (16 * NNODES)        // 8388608
#define NWORDS     (NUM_GRAPHS * 32)    // 16384 table entries (u64 each)

typedef int   int4v   __attribute__((ext_vector_type(4)));
typedef float float4v __attribute__((ext_vector_type(4)));

__device__ __forceinline__ unsigned rotl32(unsigned v, int d) {
  return (v << d) | (v >> (32 - d));
}

// JAX threefry2x32: 20 rounds, 5 key injections.
__device__ __forceinline__ void tf2x32(unsigned k0, unsigned k1,
                                       unsigned x0, unsigned x1,
                                       unsigned& o0, unsigned& o1) {
  unsigned ks2 = k0 ^ k1 ^ 0x1BD11BDAu;
  x0 += k0; x1 += k1;
  x0 += x1; x1 = rotl32(x1, 13); x1 ^= x0;
  x0 += x1; x1 = rotl32(x1, 15); x1 ^= x0;
  x0 += x1; x1 = rotl32(x1, 26); x1 ^= x0;
  x0 += x1; x1 = rotl32(x1, 6);  x1 ^= x0;
  x0 += k1; x1 += ks2 + 1u;
  x0 += x1; x1 = rotl32(x1, 17); x1 ^= x0;
  x0 += x1; x1 = rotl32(x1, 29); x1 ^= x0;
  x0 += x1; x1 = rotl32(x1, 16); x1 ^= x0;
  x0 += x1; x1 = rotl32(x1, 24); x1 ^= x0;
  x0 += ks2; x1 += k0 + 2u;
  x0 += x1; x1 = rotl32(x1, 13); x1 ^= x0;
  x0 += x1; x1 = rotl32(x1, 15); x1 ^= x0;
  x0 += x1; x1 = rotl32(x1, 26); x1 ^= x0;
  x0 += x1; x1 = rotl32(x1, 6);  x1 ^= x0;
  x0 += k0; x1 += k1 + 3u;
  x0 += x1; x1 = rotl32(x1, 17); x1 ^= x0;
  x0 += x1; x1 = rotl32(x1, 29); x1 ^= x0;
  x0 += x1; x1 = rotl32(x1, 16); x1 ^= x0;
  x0 += x1; x1 = rotl32(x1, 24); x1 ^= x0;
  x0 += k1; x1 += ks2 + 4u;
  x0 += x1; x1 = rotl32(x1, 13); x1 ^= x0;
  x0 += x1; x1 = rotl32(x1, 15); x1 ^= x0;
  x0 += x1; x1 = rotl32(x1, 26); x1 ^= x0;
  x0 += x1; x1 = rotl32(x1, 6);  x1 ^= x0;
  x0 += ks2; x1 += k0 + 5u;
  o0 = x0; o1 = x1;
}

// One block (512 thr) per graph.
// Selection = "512 smallest (key<<32|idx) u64s" — found via O(N) histogram
// threshold instead of a bitonic sort (all u64s distinct: idx embedded, so
// flag[i] = (skey_i <= T) with T = 512th-smallest is EXACT, tie-safe).
// Then flags -> prefix scan -> ids (sorted by index), packed (bitmap,base)
// table entry per 32 nodes, out_b/out_p, and the x-row gather for this graph
// (each block owns out rows [g*512, g*512+512) — no ids workspace needed).
__global__ __launch_bounds__(512) void select_kernel(
    const float* __restrict__ x, float* __restrict__ out_x,
    float* __restrict__ out_b, float* __restrict__ out_p,
    unsigned long long* __restrict__ tab) {
  __shared__ int flags[NPG];                 // 4 KB
  __shared__ short ids[KSEL];                // 1 KB
  __shared__ int ssum[512];                  // 2 KB
  __shared__ int bins[256];                  // 1 KB
  __shared__ int binsum[256];                // 1 KB
  __shared__ unsigned long long cand[NPG];   // 8 KB (capacity-safe)
  __shared__ int ccnt;
  __shared__ int sB, sR;
  __shared__ unsigned long long sT;

  const int g = blockIdx.x;
  const int tid = threadIdx.x;

  unsigned kg0, kg1, sk0, sk1;
  tf2x32(0u, 42u, 0u, (unsigned)g, kg0, kg1);
  tf2x32(kg0, kg1, 0u, 1u, sk0, sk1);

  if (tid < 256) bins[tid] = 0;
  if (tid == 0) ccnt = 0;

  // keygen: 2 elements/thread, kept in registers (no skeys array needed)
  unsigned long long myk[2];
#pragma unroll
  for (int e = 0; e < 2; ++e) {
    int i = tid + e * 512;
    unsigned b1, b2;
    tf2x32(sk0, sk1, 0u, (unsigned)i, b1, b2);
    unsigned key = b1 ^ b2;
    myk[e] = ((unsigned long long)key << 32) | (unsigned)i;
  }
  __syncthreads();

  // histogram on top 8 bits of key
#pragma unroll
  for (int e = 0; e < 2; ++e)
    atomicAdd(&bins[(int)(myk[e] >> 56)], 1);
  __syncthreads();

  // inclusive scan over 256 bins
  if (tid < 256) binsum[tid] = bins[tid];
  __syncthreads();
  for (int off = 1; off < 256; off <<= 1) {
    int v = 0;
    if (tid < 256 && tid >= off) v = binsum[tid - off];
    __syncthreads();
    if (tid < 256) binsum[tid] += v;
    __syncthreads();
  }
  // find crossing bin b*: cum_excl < KSEL <= cum_incl
  if (tid < 256) {
    int incl = binsum[tid];
    int excl = incl - bins[tid];
    if (excl < KSEL && KSEL <= incl) { sB = tid; sR = KSEL - excl; }
  }
  __syncthreads();
  const int bstar = sB;
  const int r = sR;

  // collect candidates in bin b*
#pragma unroll
  for (int e = 0; e < 2; ++e) {
    if ((int)(myk[e] >> 56) == bstar) {
      int p = atomicAdd(&ccnt, 1);
      cand[p] = myk[e];
    }
  }
  __syncthreads();
  const int cnt = ccnt;
  // exact rank among candidates; T = r-th smallest in bin (rank r-1)
  if (tid < 64) {
    for (int c = tid; c < cnt; c += 64) {
      unsigned long long mine = cand[c];
      int rank = 0;
      for (int j = 0; j < cnt; ++j) rank += (cand[j] < mine) ? 1 : 0;
      if (rank == r - 1) sT = mine;
    }
  }
  __syncthreads();
  const unsigned long long T = sT;

  // flags[i] = selected
#pragma unroll
  for (int e = 0; e < 2; ++e) {
    int i = tid + e * 512;
    flags[i] = (myk[e] <= T) ? 1 : 0;
  }
  __syncthreads();

  // exclusive prefix scan over 1024 flags (2/thread)
  int i2 = tid * 2;
  int f0 = flags[i2], f1 = flags[i2 + 1];
  int local = f0 + f1;
  ssum[tid] = local;
  __syncthreads();
  for (int off = 1; off < 512; off <<= 1) {
    int v = (tid >= off) ? ssum[tid - off] : 0;
    __syncthreads();
    ssum[tid] += v;
    __syncthreads();
  }
  int pos = ssum[tid] - local;

  // scatter ids / batch / perm
  {
    int i = i2;
    int node = g * NPG + i;
    if (f0) {
      ids[pos] = (short)i;
      out_b[g * KSEL + pos] = (float)g;
      out_p[g * KSEL + pos] = (float)node;
      pos++;
    }
    if (f1) {
      ids[pos] = (short)(i + 1);
      out_b[g * KSEL + pos] = (float)g;
      out_p[g * KSEL + pos] = (float)(node + 1);
    }
  }

  // packed lookup table: per 32 nodes, bitmap word + exclusive base
  if (tid < 32) {
    unsigned w = 0;
#pragma unroll
    for (int j = 0; j < 32; ++j) w |= ((unsigned)(flags[tid * 32 + j] & 1)) << j;
    unsigned base = (tid == 0) ? 0u : (unsigned)ssum[tid * 16 - 1];
    tab[g * 32 + tid] = (unsigned long long)w |
                        ((unsigned long long)base << 32);
  }
  __syncthreads();

  // gather x rows for this graph: 512 rows x 16 float4, coalesced per row
  {
    const float4v* xs = (const float4v*)x + (size_t)g * (NPG * 16);
    float4v* xd = (float4v*)out_x + (size_t)g * (KSEL * 16);
#pragma unroll
    for (int k = 0; k < 16; ++k) {
      int t = k * 512 + tid;
      int rr = t >> 4;          // out row 0..511
      int c = t & 15;
      int id = (int)ids[rr];
      float4v v = __builtin_nontemporal_load(&xs[id * 16 + c]);
      __builtin_nontemporal_store(v, &xd[rr * 16 + c]);
    }
  }
}

// Edge filter only. 256 blocks x 1024 thr, full (bitmap,base) table in LDS:
// every endpoint lookup is one scattered ds_read_b64 + popcount.
__global__ __launch_bounds__(1024) void edge_kernel(
    const int* __restrict__ ei,
    const unsigned long long* __restrict__ tab,
    float* __restrict__ out_e) {
  __shared__ unsigned long long ltab[NWORDS];   // 128 KB

  const int tid = threadIdx.x;
  const int blk = blockIdx.x;

  // stage table (16 u64 per thread, coalesced)
#pragma unroll
  for (int k = 0; k < NWORDS / 1024; ++k) {
    ltab[k * 1024 + tid] = tab[k * 1024 + tid];
  }
  __syncthreads();

  // 32 edges per thread, 4 chunks of 8
#pragma unroll
  for (int k = 0; k < 4; ++k) {
    const int base = (((k * 256 + blk) * 1024) + tid) * 8;
    int4v s0 = __builtin_nontemporal_load((const int4v*)(ei + base));
    int4v s1 = __builtin_nontemporal_load((const int4v*)(ei + base + 4));
    int4v d0 = __builtin_nontemporal_load((const int4v*)(ei + (size_t)NEDGE + base));
    int4v d1 = __builtin_nontemporal_load((const int4v*)(ei + (size_t)NEDGE + base + 4));

    int src[8] = {s0.x, s0.y, s0.z, s0.w, s1.x, s1.y, s1.z, s1.w};
    int dst[8] = {d0.x, d0.y, d0.z, d0.w, d1.x, d1.y, d1.z, d1.w};

    int rrow[8], rcol[8];
#pragma unroll
    for (int j = 0; j < 8; ++j) {
      unsigned long long es = ltab[src[j] >> 5];
      unsigned long long ed = ltab[dst[j] >> 5];
      unsigned ws = (unsigned)es, wd = (unsigned)ed;
      int shs = src[j] & 31, shd = dst[j] & 31;
      bool sels = (ws >> shs) & 1u;
      bool seld = (wd >> shd) & 1u;
      int poss = (int)(es >> 32) + __popc(ws & ((1u << shs) - 1u));
      int posd = (int)(ed >> 32) + __popc(wd & ((1u << shd) - 1u));
      bool keep = sels && seld;
      rrow[j] = keep ? (((src[j] & ~1023) >> 1) + poss) : -1;
      rcol[j] = keep ? (((dst[j] & ~1023) >> 1) + posd) : -1;
    }

    float4v r0 = {(float)rrow[0], (float)rrow[1], (float)rrow[2], (float)rrow[3]};
    float4v r1 = {(float)rrow[4], (float)rrow[5], (float)rrow[6], (float)rrow[7]};
    float4v c0 = {(float)rcol[0], (float)rcol[1], (float)rcol[2], (float)rcol[3]};
    float4v c1 = {(float)rcol[4], (float)rcol[5], (float)rcol[6], (float)rcol[7]};
    __builtin_nontemporal_store(r0, (float4v*)(out_e + base));
    __builtin_nontemporal_store(r1, (float4v*)(out_e + base + 4));
    __builtin_nontemporal_store(c0, (float4v*)(out_e + (size_t)NEDGE + base));
    __builtin_nontemporal_store(c1, (float4v*)(out_e + (size_t)NEDGE + base + 4));
  }
}

extern "C" void kernel_launch(void* const* d_in, const int* in_sizes, int n_in,
                              void* d_out, int out_size, void* d_ws, size_t ws_size,
                              hipStream_t stream) {
  const float* x  = (const float*)d_in[0];
  const int*   ei = (const int*)d_in[1];

  float* out   = (float*)d_out;
  float* out_x = out;                                            // 16777216
  float* out_e = out + (size_t)NUM_GRAPHS * KSEL * CFEAT;        // 16777216
  float* out_b = out_e + 2 * (size_t)NEDGE;                      // 262144
  float* out_p = out_b + (size_t)NUM_GRAPHS * KSEL;              // 262144

  // d_ws layout: [0,128K) u64 table
  unsigned long long* tab = (unsigned long long*)d_ws;

  select_kernel<<<NUM_GRAPHS, 512, 0, stream>>>(x, out_x, out_b, out_p, tab);
  edge_kernel<<<256, 1024, 0, stream>>>(ei, tab, out_e);
}